// Round 3
// baseline (523.181 us; speedup 1.0000x reference)
//
#include <hip/hip_runtime.h>
#include <hip/hip_bf16.h>
#include <stdint.h>

#define N_NODES 100000
#define N_EDGES 1200000
#define IN_CH 64
#define HID 16
#define OUT_CH 64

typedef __hip_bfloat16 bf16;

__device__ __forceinline__ float b2f(bf16 v) { return __bfloat162float(v); }
__device__ __forceinline__ float lo_f(uint32_t p) { return __uint_as_float(p << 16); }
__device__ __forceinline__ float hi_f(uint32_t p) { return __uint_as_float(p & 0xffff0000u); }

__device__ __forceinline__ float loadf(const void* p, int i, int bf) {
    return bf ? b2f(((const bf16*)p)[i]) : ((const float*)p)[i];
}
__device__ __forceinline__ int loadi(const int* p, int i, int i64) {
    return i64 ? p[2 * i] : p[i];
}

// Detect dtypes; fold layer-1 edge projection through W1l.
__global__ void k_prep(const void* __restrict__ x, const int* __restrict__ ei,
                       const void* __restrict__ W1e, const void* __restrict__ b1e,
                       const void* __restrict__ W1l, float* __restrict__ wc,
                       int* __restrict__ flags) {
    __shared__ int s_bf;
    if (threadIdx.x == 0) {
        const uint16_t* u = (const uint16_t*)x;
        int cnt = 0;
        for (int i = 0; i < 64; ++i) {
            int e = (u[i] >> 7) & 0xff;
            cnt += (e >= 100 && e <= 140);
        }
        int bf = (cnt >= 50);
        const uint32_t* w = (const uint32_t*)ei;
        int z = 0;
        for (int i = 1; i < 64; i += 2) z += (w[i] == 0u);
        flags[0] = bf;
        flags[1] = (z >= 16);
        s_bf = bf;
    }
    __syncthreads();
    int bf = s_bf;
    int j = threadIdx.x;
    if (j >= HID) return;
    for (int r = 0; r < 3; ++r) {
        float s = 0.f;
        for (int k = 0; k < IN_CH; ++k)
            s += loadf(W1e, r * IN_CH + k, bf) * loadf(W1l, k * HID + j, bf);
        wc[r * HID + j] = s;
    }
    float s = 0.f;
    for (int k = 0; k < IN_CH; ++k)
        s += loadf(b1e, k, bf) * loadf(W1l, k * HID + j, bf);
    wc[3 * HID + j] = s;
}

// Histogram + edge-attr sums: deg_i[dst]++, sa[dst] += ea[e].  4 lanes/edge.
__global__ void __launch_bounds__(256) k_hist(const int* __restrict__ ei,
                                              const void* __restrict__ ea,
                                              const int* __restrict__ flags,
                                              int* __restrict__ deg_i,
                                              float* __restrict__ sa) {
    int tid = blockIdx.x * 256 + threadIdx.x;
    int e = tid >> 2;
    if (e >= N_EDGES) return;
    int c = tid & 3;
    int i64 = flags[1], bf = flags[0];
    int dst = loadi(ei, N_EDGES + e, i64);
    if (c < 3)
        atomicAdd(&sa[dst * 3 + c], loadf(ea, e * 3 + c, bf));
    else
        atomicAdd(&deg_i[dst], 1);
}

// Disjoint CSR ranges (order-free) + float degree.
__global__ void __launch_bounds__(256) k_off(const int* __restrict__ deg_i,
                                             int* __restrict__ cnt,
                                             int* __restrict__ off,
                                             int* __restrict__ pos,
                                             float* __restrict__ degf) {
    int i = blockIdx.x * 256 + threadIdx.x;
    if (i >= N_NODES) return;
    int d = deg_i[i];
    int o = atomicAdd(cnt, d);
    off[i] = o;
    pos[i] = o;
    degf[i] = (float)d;
}

// Scatter src ids into CSR slots.
__global__ void __launch_bounds__(256) k_scatter(const int* __restrict__ ei,
                                                 const int* __restrict__ flags,
                                                 int* __restrict__ pos,
                                                 int* __restrict__ srcs) {
    int e = blockIdx.x * 256 + threadIdx.x;
    if (e >= N_EDGES) return;
    int i64 = flags[1];
    int src = loadi(ei, e, i64);
    int dst = loadi(ei, N_EDGES + e, i64);
    int slot = atomicAdd(&pos[dst], 1);
    srcs[slot] = src;
}

// y = x @ W1l  (N x 16), 16 threads per row
__global__ void __launch_bounds__(256) k_y(const void* __restrict__ x,
                                           const void* __restrict__ W1l,
                                           const int* __restrict__ flags,
                                           float* __restrict__ y) {
    __shared__ float w[IN_CH * HID];
    int bf = flags[0];
    for (int t = threadIdx.x; t < IN_CH * HID; t += 256) w[t] = loadf(W1l, t, bf);
    __syncthreads();
    int tid = blockIdx.x * 256 + threadIdx.x;
    int row = tid >> 4;
    if (row >= N_NODES) return;
    int c = tid & 15;
    float acc = 0.f;
    if (bf) {
        const uint32_t* xr = (const uint32_t*)x + (size_t)row * (IN_CH / 2);
#pragma unroll
        for (int k2 = 0; k2 < IN_CH / 2; ++k2) {
            uint32_t p = xr[k2];
            acc += lo_f(p) * w[(2 * k2) * HID + c] + hi_f(p) * w[(2 * k2 + 1) * HID + c];
        }
    } else {
        const float* xr = (const float*)x + (size_t)row * IN_CH;
#pragma unroll
        for (int k = 0; k < IN_CH; ++k) acc += xr[k] * w[k * HID + c];
    }
    y[row * HID + c] = acc;
}

// CSR gather-aggregate: outv[i][c] = sum over in-edges of in[src][c]. 16 lanes/node.
__global__ void __launch_bounds__(256) k_agg(const int* __restrict__ srcs,
                                             const int* __restrict__ off,
                                             const int* __restrict__ deg_i,
                                             const float* __restrict__ in,
                                             float* __restrict__ outv) {
    int tid = blockIdx.x * 256 + threadIdx.x;
    int i = tid >> 4;
    if (i >= N_NODES) return;
    int c = tid & 15;
    int o = off[i];
    int d = deg_i[i];
    float s = 0.f;
    if (d > 0) {
        int src = srcs[o];
        for (int k = 1; k < d; ++k) {
            int nsrc = srcs[o + k];              // prefetch next src
            s += in[(size_t)src * HID + c];
            src = nsrc;
        }
        s += in[(size_t)src * HID + c];
    }
    outv[i * HID + c] = s;
}

// ---- fallback (atomic) edge kernels, used only if ws too small ----
__global__ void __launch_bounds__(256) k_edge1(const int* __restrict__ ei,
                                               const void* __restrict__ ea,
                                               const int* __restrict__ flags,
                                               const float* __restrict__ y,
                                               float* __restrict__ sy,
                                               float* __restrict__ sa,
                                               float* __restrict__ deg) {
    int tid = blockIdx.x * 256 + threadIdx.x;
    int e = tid >> 4;
    if (e >= N_EDGES) return;
    int c = tid & 15;
    int i64 = flags[1], bf = flags[0];
    int src = loadi(ei, e, i64);
    int dst = loadi(ei, N_EDGES + e, i64);
    atomicAdd(&sy[dst * HID + c], y[src * HID + c]);
    if (c < 3)
        atomicAdd(&sa[dst * 3 + c], loadf(ea, e * 3 + c, bf));
    else if (c == 3)
        atomicAdd(&deg[dst], 1.0f);
}

__global__ void __launch_bounds__(256) k_edge2(const int* __restrict__ ei,
                                               const int* __restrict__ flags,
                                               const float* __restrict__ h,
                                               float* __restrict__ sh) {
    int tid = blockIdx.x * 256 + threadIdx.x;
    int e = tid >> 4;
    if (e >= N_EDGES) return;
    int c = tid & 15;
    int i64 = flags[1];
    int src = loadi(ei, e, i64);
    int dst = loadi(ei, N_EDGES + e, i64);
    atomicAdd(&sh[dst * HID + c], h[src * HID + c]);
}
// -------------------------------------------------------------------

// h = relu((sy + sa@wc + deg*bc)/max(deg,1) + b1l + b1r + x@W1r)  [in-place over sy]
__global__ void __launch_bounds__(256) k_h(float* __restrict__ syh,
                                           const float* __restrict__ sa,
                                           const float* __restrict__ degf,
                                           const void* __restrict__ x,
                                           const void* __restrict__ W1r,
                                           const void* __restrict__ b1l,
                                           const void* __restrict__ b1r,
                                           const float* __restrict__ wc,
                                           const int* __restrict__ flags) {
    __shared__ float wr[IN_CH * HID];
    __shared__ float bsum[HID];
    int bf = flags[0];
    for (int t = threadIdx.x; t < IN_CH * HID; t += 256) wr[t] = loadf(W1r, t, bf);
    if (threadIdx.x < HID)
        bsum[threadIdx.x] = loadf(b1l, threadIdx.x, bf) + loadf(b1r, threadIdx.x, bf);
    __syncthreads();
    int tid = blockIdx.x * 256 + threadIdx.x;
    int i = tid >> 4;
    if (i >= N_NODES) return;
    int c = tid & 15;
    float zc = 0.f;
    if (bf) {
        const uint32_t* xr = (const uint32_t*)x + (size_t)i * (IN_CH / 2);
#pragma unroll
        for (int k2 = 0; k2 < IN_CH / 2; ++k2) {
            uint32_t p = xr[k2];
            zc += lo_f(p) * wr[(2 * k2) * HID + c] + hi_f(p) * wr[(2 * k2 + 1) * HID + c];
        }
    } else {
        const float* xr = (const float*)x + (size_t)i * IN_CH;
#pragma unroll
        for (int k = 0; k < IN_CH; ++k) zc += xr[k] * wr[k * HID + c];
    }
    float d = degf[i];
    float inv = 1.0f / fmaxf(d, 1.0f);
    float s0 = sa[i * 3 + 0], s1 = sa[i * 3 + 1], s2 = sa[i * 3 + 2];
    float acc = syh[i * HID + c] + s0 * wc[c] + s1 * wc[HID + c] + s2 * wc[2 * HID + c] +
                d * wc[3 * HID + c];
    float v = acc * inv + bsum[c] + zc;
    syh[i * HID + c] = fmaxf(v, 0.0f);
}

// out = ((sh + sa@W2e + deg*b2e)/max(deg,1)) @ W2l + h @ W2r + b2l + b2r
__global__ void __launch_bounds__(256) k_out(const float* __restrict__ sh,
                                             const float* __restrict__ sa,
                                             const float* __restrict__ degf,
                                             const float* __restrict__ h,
                                             const void* __restrict__ W2l,
                                             const void* __restrict__ b2l,
                                             const void* __restrict__ W2r,
                                             const void* __restrict__ b2r,
                                             const void* __restrict__ W2e,
                                             const void* __restrict__ b2e,
                                             const int* __restrict__ flags,
                                             void* __restrict__ out) {
    __shared__ float wl[HID * OUT_CH];
    __shared__ float wr[HID * OUT_CH];
    __shared__ float we[3 * HID];
    __shared__ float be[HID];
    __shared__ float bb[OUT_CH];
    int bf = flags[0];
    for (int t = threadIdx.x; t < HID * OUT_CH; t += 256) {
        wl[t] = loadf(W2l, t, bf);
        wr[t] = loadf(W2r, t, bf);
    }
    if (threadIdx.x < 3 * HID) we[threadIdx.x] = loadf(W2e, threadIdx.x, bf);
    if (threadIdx.x < HID) be[threadIdx.x] = loadf(b2e, threadIdx.x, bf);
    if (threadIdx.x < OUT_CH)
        bb[threadIdx.x] = loadf(b2l, threadIdx.x, bf) + loadf(b2r, threadIdx.x, bf);
    __syncthreads();
    int tid = blockIdx.x * 256 + threadIdx.x;
    int i = tid >> 6;
    if (i >= N_NODES) return;
    int j = tid & 63;
    float d = degf[i];
    float inv = 1.0f / fmaxf(d, 1.0f);
    float s0 = sa[i * 3 + 0], s1 = sa[i * 3 + 1], s2 = sa[i * 3 + 2];
    float o = bb[j];
#pragma unroll
    for (int c = 0; c < HID; ++c) {
        float t = (sh[i * HID + c] + s0 * we[c] + s1 * we[HID + c] + s2 * we[2 * HID + c] +
                   d * be[c]) * inv;
        o += t * wl[c * OUT_CH + j];
        o += h[i * HID + c] * wr[c * OUT_CH + j];
    }
    if (bf)
        ((bf16*)out)[i * OUT_CH + j] = __float2bfloat16(o);
    else
        ((float*)out)[i * OUT_CH + j] = o;
}

extern "C" void kernel_launch(void* const* d_in, const int* in_sizes, int n_in,
                              void* d_out, int out_size, void* d_ws, size_t ws_size,
                              hipStream_t stream) {
    const void* x   = d_in[0];
    const int*  ei  = (const int*)d_in[1];
    const void* ea  = d_in[2];
    const void* W1l = d_in[3];
    const void* b1l = d_in[4];
    const void* W1r = d_in[5];
    const void* b1r = d_in[6];
    const void* W1e = d_in[7];
    const void* b1e = d_in[8];
    const void* W2l = d_in[9];
    const void* b2l = d_in[10];
    const void* W2r = d_in[11];
    const void* b2r = d_in[12];
    const void* W2e = d_in[13];
    const void* b2e = d_in[14];

    const size_t N16 = (size_t)N_NODES * HID;
    float* ws   = (float*)d_ws;
    float* bufA = ws;                              // y, then sh
    float* bufB = bufA + N16;                      // sy, then h (in-place)
    float* sa   = bufB + N16;                      // 3N  (zeroed)
    float* degf = sa + (size_t)3 * N_NODES;        // N
    int*  deg_i = (int*)(degf + N_NODES);          // N   (zeroed, CSR)
    int*  cnt   = deg_i + N_NODES;                 // 1   (zeroed, CSR)
    int*  off   = cnt + 1;                         // N   (CSR)
    int*  pos   = off + N_NODES;                   // N   (CSR)
    int*  srcs  = pos + N_NODES;                   // E   (CSR)
    float* wc   = (float*)(srcs + N_EDGES);        // 64
    int* flags  = (int*)(wc + 64);                 // 2

    size_t need_csr = (size_t)((char*)(flags + 2) - (char*)d_ws);
    bool use_csr = ws_size >= need_csr;

    k_prep<<<1, 64, 0, stream>>>(x, ei, W1e, b1e, W1l, wc, flags);
    k_y<<<(N_NODES * 16 + 255) / 256, 256, 0, stream>>>(x, W1l, flags, bufA);

    if (use_csr) {
        // zero: sa, degf, deg_i, cnt (contiguous)
        hipMemsetAsync(sa, 0, (size_t)(5 * N_NODES + 1) * sizeof(float), stream);
        k_hist<<<(N_EDGES * 4 + 255) / 256, 256, 0, stream>>>(ei, ea, flags, deg_i, sa);
        k_off<<<(N_NODES + 255) / 256, 256, 0, stream>>>(deg_i, cnt, off, pos, degf);
        k_scatter<<<(N_EDGES + 255) / 256, 256, 0, stream>>>(ei, flags, pos, srcs);
        // sy = aggregate(y)
        k_agg<<<(N_NODES * 16 + 255) / 256, 256, 0, stream>>>(srcs, off, deg_i, bufA, bufB);
        k_h<<<(N_NODES * 16 + 255) / 256, 256, 0, stream>>>(bufB, sa, degf, x, W1r, b1l,
                                                            b1r, wc, flags);
        // sh = aggregate(h)  (bufA's y is dead)
        k_agg<<<(N_NODES * 16 + 255) / 256, 256, 0, stream>>>(srcs, off, deg_i, bufB, bufA);
    } else {
        // fallback: zero sy, sa, degf (contiguous)
        hipMemsetAsync(bufB, 0, (N16 + (size_t)4 * N_NODES) * sizeof(float), stream);
        k_edge1<<<(N_EDGES * 16 + 255) / 256, 256, 0, stream>>>(ei, ea, flags, bufA, bufB,
                                                                sa, degf);
        k_h<<<(N_NODES * 16 + 255) / 256, 256, 0, stream>>>(bufB, sa, degf, x, W1r, b1l,
                                                            b1r, wc, flags);
        hipMemsetAsync(bufA, 0, N16 * sizeof(float), stream);
        k_edge2<<<(N_EDGES * 16 + 255) / 256, 256, 0, stream>>>(ei, flags, bufB, bufA);
    }

    k_out<<<(N_NODES * 64 + 255) / 256, 256, 0, stream>>>(bufA, sa, degf, bufB, W2l, b2l,
                                                          W2r, b2r, W2e, b2e, flags, d_out);
}

// Round 4
// 484.260 us; speedup vs baseline: 1.0804x; 1.0804x over previous
//
#include <hip/hip_runtime.h>
#include <hip/hip_bf16.h>
#include <stdint.h>

#define N_NODES 100000
#define N_EDGES 1200000
#define IN_CH 64
#define HID 16
#define OUT_CH 64

typedef __hip_bfloat16 bf16;

__device__ __forceinline__ float b2f(bf16 v) { return __bfloat162float(v); }
__device__ __forceinline__ float lo_f(uint32_t p) { return __uint_as_float(p << 16); }
__device__ __forceinline__ float hi_f(uint32_t p) { return __uint_as_float(p & 0xffff0000u); }

__device__ __forceinline__ float loadf(const void* p, size_t i, int bf) {
    return bf ? b2f(((const bf16*)p)[i]) : ((const float*)p)[i];
}
__device__ __forceinline__ int loadi(const int* p, size_t i, int i64) {
    return i64 ? p[2 * i] : p[i];
}
__device__ __forceinline__ float ldv(const float* p) { return *p; }
__device__ __forceinline__ float ldv(const bf16* p) { return b2f(*p); }
__device__ __forceinline__ void stv(float* p, float v) { *p = v; }
__device__ __forceinline__ void stv(bf16* p, float v) { *p = __float2bfloat16(v); }

// Detect dtypes; fold layer-1 edge projection through W1l.
// wc[0..47] = W1e @ W1l (3x16), wc[48..63] = b1e @ W1l
__global__ void k_prep(const void* __restrict__ x, const int* __restrict__ ei,
                       const void* __restrict__ W1e, const void* __restrict__ b1e,
                       const void* __restrict__ W1l, float* __restrict__ wc,
                       int* __restrict__ flags) {
    __shared__ int s_bf;
    if (threadIdx.x == 0) {
        const uint16_t* u = (const uint16_t*)x;
        int cnt = 0;
        for (int i = 0; i < 64; ++i) {
            int e = (u[i] >> 7) & 0xff;
            cnt += (e >= 100 && e <= 140);
        }
        int bf = (cnt >= 50);
        const uint32_t* w = (const uint32_t*)ei;
        int z = 0;
        for (int i = 1; i < 64; i += 2) z += (w[i] == 0u);
        flags[0] = bf;
        flags[1] = (z >= 16);
        s_bf = bf;
    }
    __syncthreads();
    int bf = s_bf;
    int j = threadIdx.x;
    if (j >= HID) return;
    for (int r = 0; r < 3; ++r) {
        float s = 0.f;
        for (int k = 0; k < IN_CH; ++k)
            s += loadf(W1e, r * IN_CH + k, bf) * loadf(W1l, k * HID + j, bf);
        wc[r * HID + j] = s;
    }
    float s = 0.f;
    for (int k = 0; k < IN_CH; ++k)
        s += loadf(b1e, k, bf) * loadf(W1l, k * HID + j, bf);
    wc[3 * HID + j] = s;
}

// Pure degree histogram: 1 thread/edge, int atomics only.
__global__ void __launch_bounds__(256) k_hist(const int* __restrict__ ei,
                                              const int* __restrict__ flags,
                                              int* __restrict__ deg_i) {
    int e = blockIdx.x * 256 + threadIdx.x;
    if (e >= N_EDGES) return;
    int dst = loadi(ei, (size_t)N_EDGES + e, flags[1]);
    atomicAdd(&deg_i[dst], 1);
}

// Disjoint CSR range starts (order-free).
__global__ void __launch_bounds__(256) k_off(const int* __restrict__ deg_i,
                                             int* __restrict__ cnt,
                                             int* __restrict__ off) {
    int i = blockIdx.x * 256 + threadIdx.x;
    if (i >= N_NODES) return;
    off[i] = atomicAdd(cnt, deg_i[i]);
}

// Scatter {src, edge_id} into CSR slots; off becomes range END afterwards.
__global__ void __launch_bounds__(256) k_scatter(const int* __restrict__ ei,
                                                 const int* __restrict__ flags,
                                                 int* __restrict__ off,
                                                 uint2* __restrict__ slots) {
    int e = blockIdx.x * 256 + threadIdx.x;
    if (e >= N_EDGES) return;
    int i64 = flags[1];
    int src = loadi(ei, e, i64);
    int dst = loadi(ei, (size_t)N_EDGES + e, i64);
    int slot = atomicAdd(&off[dst], 1);
    slots[slot] = make_uint2((unsigned)src, (unsigned)e);
}

// y = x @ W1l  (N x 16, bf16 out), 16 threads per row
__global__ void __launch_bounds__(256) k_y(const void* __restrict__ x,
                                           const void* __restrict__ W1l,
                                           const int* __restrict__ flags,
                                           bf16* __restrict__ y) {
    __shared__ float w[IN_CH * HID];
    int bf = flags[0];
    for (int t = threadIdx.x; t < IN_CH * HID; t += 256) w[t] = loadf(W1l, t, bf);
    __syncthreads();
    int tid = blockIdx.x * 256 + threadIdx.x;
    int row = tid >> 4;
    if (row >= N_NODES) return;
    int c = tid & 15;
    float acc = 0.f;
    if (bf) {
        const uint32_t* xr = (const uint32_t*)x + (size_t)row * (IN_CH / 2);
#pragma unroll
        for (int k2 = 0; k2 < IN_CH / 2; ++k2) {
            uint32_t p = xr[k2];
            acc += lo_f(p) * w[(2 * k2) * HID + c] + hi_f(p) * w[(2 * k2 + 1) * HID + c];
        }
    } else {
        const float* xr = (const float*)x + (size_t)row * IN_CH;
#pragma unroll
        for (int k = 0; k < IN_CH; ++k) acc += xr[k] * w[k * HID + c];
    }
    y[row * HID + c] = __float2bfloat16(acc);
}

// CSR gather-aggregate, 64 lanes/node (4 edges in flight), shfl reduce.
// ATTR=1: also reduce sa[i] = sum of ea over in-edges (lanes c<3).
template <int ATTR, typename TS>
__global__ void __launch_bounds__(256) k_agg(const uint2* __restrict__ slots,
                                             const int* __restrict__ off,
                                             const int* __restrict__ deg_i,
                                             const bf16* __restrict__ in,
                                             const void* __restrict__ ea,
                                             const int* __restrict__ flags,
                                             TS* __restrict__ outv,
                                             float* __restrict__ sa) {
    int tid = blockIdx.x * 256 + threadIdx.x;
    int i = tid >> 6;
    if (i >= N_NODES) return;
    int lane = tid & 63;
    int c = lane & 15;
    int sub = lane >> 4;
    int bf = ATTR ? flags[0] : 0;
    int d = deg_i[i];
    int start = off[i] - d;  // off holds range END after k_scatter
    float s = 0.f, t = 0.f;
    int k = sub;
    for (; k + 4 < d; k += 8) {  // two gathers in flight
        uint2 sl0 = slots[start + k];
        uint2 sl1 = slots[start + k + 4];
        float v0 = b2f(in[(size_t)sl0.x * HID + c]);
        float v1 = b2f(in[(size_t)sl1.x * HID + c]);
        s += v0 + v1;
        if (ATTR && c < 3)
            t += loadf(ea, (size_t)sl0.y * 3 + c, bf) + loadf(ea, (size_t)sl1.y * 3 + c, bf);
    }
    if (k < d) {
        uint2 sl = slots[start + k];
        s += b2f(in[(size_t)sl.x * HID + c]);
        if (ATTR && c < 3) t += loadf(ea, (size_t)sl.y * 3 + c, bf);
    }
    s += __shfl_xor(s, 16, 64);
    s += __shfl_xor(s, 32, 64);
    if (ATTR) {
        t += __shfl_xor(t, 16, 64);
        t += __shfl_xor(t, 32, 64);
    }
    if (sub == 0) {
        stv(&outv[(size_t)i * HID + c], s);
        if (ATTR && c < 3) sa[i * 3 + c] = t;
    }
}

// h = relu((sy + sa@wc + deg*wc3)/max(deg,1) + b1l + b1r + x@W1r)  -> bf16
template <typename TS>
__global__ void __launch_bounds__(256) k_h(const TS* __restrict__ syb,
                                           const float* __restrict__ sa,
                                           const int* __restrict__ deg_i,
                                           const void* __restrict__ x,
                                           const void* __restrict__ W1r,
                                           const void* __restrict__ b1l,
                                           const void* __restrict__ b1r,
                                           const float* __restrict__ wc,
                                           const int* __restrict__ flags,
                                           bf16* __restrict__ h) {
    __shared__ float wr[IN_CH * HID];
    __shared__ float bsum[HID];
    int bf = flags[0];
    for (int t = threadIdx.x; t < IN_CH * HID; t += 256) wr[t] = loadf(W1r, t, bf);
    if (threadIdx.x < HID)
        bsum[threadIdx.x] = loadf(b1l, threadIdx.x, bf) + loadf(b1r, threadIdx.x, bf);
    __syncthreads();
    int tid = blockIdx.x * 256 + threadIdx.x;
    int i = tid >> 4;
    if (i >= N_NODES) return;
    int c = tid & 15;
    float zc = 0.f;
    if (bf) {
        const uint32_t* xr = (const uint32_t*)x + (size_t)i * (IN_CH / 2);
#pragma unroll
        for (int k2 = 0; k2 < IN_CH / 2; ++k2) {
            uint32_t p = xr[k2];
            zc += lo_f(p) * wr[(2 * k2) * HID + c] + hi_f(p) * wr[(2 * k2 + 1) * HID + c];
        }
    } else {
        const float* xr = (const float*)x + (size_t)i * IN_CH;
#pragma unroll
        for (int k = 0; k < IN_CH; ++k) zc += xr[k] * wr[k * HID + c];
    }
    float d = (float)deg_i[i];
    float inv = 1.0f / fmaxf(d, 1.0f);
    float s0 = sa[i * 3 + 0], s1 = sa[i * 3 + 1], s2 = sa[i * 3 + 2];
    float acc = ldv(&syb[(size_t)i * HID + c]) + s0 * wc[c] + s1 * wc[HID + c] +
                s2 * wc[2 * HID + c] + d * wc[3 * HID + c];
    float v = acc * inv + bsum[c] + zc;
    h[(size_t)i * HID + c] = __float2bfloat16(fmaxf(v, 0.0f));
}

// out = ((sh + sa@W2e + deg*b2e)/max(deg,1)) @ W2l + h @ W2r + b2l + b2r
template <typename TS>
__global__ void __launch_bounds__(256) k_out(const TS* __restrict__ sh,
                                             const float* __restrict__ sa,
                                             const int* __restrict__ deg_i,
                                             const bf16* __restrict__ h,
                                             const void* __restrict__ W2l,
                                             const void* __restrict__ b2l,
                                             const void* __restrict__ W2r,
                                             const void* __restrict__ b2r,
                                             const void* __restrict__ W2e,
                                             const void* __restrict__ b2e,
                                             const int* __restrict__ flags,
                                             void* __restrict__ out) {
    __shared__ float wl[HID * OUT_CH];
    __shared__ float wr[HID * OUT_CH];
    __shared__ float we[3 * HID];
    __shared__ float be[HID];
    __shared__ float bb[OUT_CH];
    int bf = flags[0];
    for (int t = threadIdx.x; t < HID * OUT_CH; t += 256) {
        wl[t] = loadf(W2l, t, bf);
        wr[t] = loadf(W2r, t, bf);
    }
    if (threadIdx.x < 3 * HID) we[threadIdx.x] = loadf(W2e, threadIdx.x, bf);
    if (threadIdx.x < HID) be[threadIdx.x] = loadf(b2e, threadIdx.x, bf);
    if (threadIdx.x < OUT_CH)
        bb[threadIdx.x] = loadf(b2l, threadIdx.x, bf) + loadf(b2r, threadIdx.x, bf);
    __syncthreads();
    int tid = blockIdx.x * 256 + threadIdx.x;
    int i = tid >> 6;
    if (i >= N_NODES) return;
    int j = tid & 63;
    float d = (float)deg_i[i];
    float inv = 1.0f / fmaxf(d, 1.0f);
    float s0 = sa[i * 3 + 0], s1 = sa[i * 3 + 1], s2 = sa[i * 3 + 2];
    float o = bb[j];
#pragma unroll
    for (int c = 0; c < HID; ++c) {
        float t = (ldv(&sh[(size_t)i * HID + c]) + s0 * we[c] + s1 * we[HID + c] +
                   s2 * we[2 * HID + c] + d * be[c]) * inv;
        o += t * wl[c * OUT_CH + j];
        o += b2f(h[(size_t)i * HID + c]) * wr[c * OUT_CH + j];
    }
    if (bf)
        ((bf16*)out)[(size_t)i * OUT_CH + j] = __float2bfloat16(o);
    else
        ((float*)out)[(size_t)i * OUT_CH + j] = o;
}

extern "C" void kernel_launch(void* const* d_in, const int* in_sizes, int n_in,
                              void* d_out, int out_size, void* d_ws, size_t ws_size,
                              hipStream_t stream) {
    const void* x   = d_in[0];
    const int*  ei  = (const int*)d_in[1];
    const void* ea  = d_in[2];
    const void* W1l = d_in[3];
    const void* b1l = d_in[4];
    const void* W1r = d_in[5];
    const void* b1r = d_in[6];
    const void* W1e = d_in[7];
    const void* b1e = d_in[8];
    const void* W2l = d_in[9];
    const void* b2l = d_in[10];
    const void* W2r = d_in[11];
    const void* b2r = d_in[12];
    const void* W2e = d_in[13];
    const void* b2e = d_in[14];

    const size_t N16 = (size_t)N_NODES * HID;
    char* p = (char*)d_ws;
    uint2* slots = (uint2*)p;            p += (size_t)N_EDGES * sizeof(uint2);   // 9.6 MB
    bf16* ybuf   = (bf16*)p;             p += N16 * sizeof(bf16);                // 3.2 MB (y then h)
    float* sa    = (float*)p;            p += (size_t)3 * N_NODES * sizeof(float); // 1.2 MB
    int* deg_i   = (int*)p;              p += (size_t)N_NODES * sizeof(int);     // 0.4 MB
    int* cnt     = (int*)p;              p += 2 * sizeof(int);  // +pad for 8B align
    int* off     = (int*)p;              p += (size_t)N_NODES * sizeof(int);     // 0.4 MB
    float* wc    = (float*)p;            p += 64 * sizeof(float);
    int* flags   = (int*)p;              p += 2 * sizeof(int);
    void* syb    = (void*)p;             // N16 * 4 (f32) or * 2 (bf16): sy then sh
    size_t base = (size_t)(p - (char*)d_ws);
    bool f32syb = ws_size >= base + N16 * sizeof(float);

    // zero deg_i + cnt (contiguous)
    hipMemsetAsync(deg_i, 0, ((size_t)N_NODES + 2) * sizeof(int), stream);

    k_prep<<<1, 64, 0, stream>>>(x, ei, W1e, b1e, W1l, wc, flags);
    k_y<<<(N_NODES * 16 + 255) / 256, 256, 0, stream>>>(x, W1l, flags, ybuf);
    k_hist<<<(N_EDGES + 255) / 256, 256, 0, stream>>>(ei, flags, deg_i);
    k_off<<<(N_NODES + 255) / 256, 256, 0, stream>>>(deg_i, cnt, off);
    k_scatter<<<(N_EDGES + 255) / 256, 256, 0, stream>>>(ei, flags, off, slots);

    dim3 gN64((N_NODES * 64 + 255) / 256), gN16((N_NODES * 16 + 255) / 256), b(256);
    if (f32syb) {
        float* sybf = (float*)syb;
        k_agg<1, float><<<gN64, b, 0, stream>>>(slots, off, deg_i, ybuf, ea, flags, sybf, sa);
        k_h<float><<<gN16, b, 0, stream>>>(sybf, sa, deg_i, x, W1r, b1l, b1r, wc, flags, ybuf);
        k_agg<0, float><<<gN64, b, 0, stream>>>(slots, off, deg_i, ybuf, ea, flags, sybf, sa);
        k_out<float><<<gN64, b, 0, stream>>>(sybf, sa, deg_i, ybuf, W2l, b2l, W2r, b2r,
                                             W2e, b2e, flags, d_out);
    } else {
        bf16* sybh = (bf16*)syb;
        k_agg<1, bf16><<<gN64, b, 0, stream>>>(slots, off, deg_i, ybuf, ea, flags, sybh, sa);
        k_h<bf16><<<gN16, b, 0, stream>>>(sybh, sa, deg_i, x, W1r, b1l, b1r, wc, flags, ybuf);
        k_agg<0, bf16><<<gN64, b, 0, stream>>>(slots, off, deg_i, ybuf, ea, flags, sybh, sa);
        k_out<bf16><<<gN64, b, 0, stream>>>(sybh, sa, deg_i, ybuf, W2l, b2l, W2r, b2r,
                                            W2e, b2e, flags, d_out);
    }
}